// Round 3
// baseline (5537.733 us; speedup 1.0000x reference)
//
#include <hip/hip_runtime.h>
#include <cstdint>
#include <cstddef>

// Problem dims (compile-time)
#define B_DIM 2
#define L_DIM 2048
#define E_DIM 1024
#define H_DIM 16
#define HD    64
#define M_ROWS (B_DIM * L_DIM)   // 4096
#define QKV_N  (3 * E_DIM)       // 3072
#define C_CONST 2.01f

// ---------------------------------------------------------------------------
// K1: qkv = x @ W_qkv + b_qkv, scattered directly into q/k/v [B,H,L,D] bufs.
// Classic fp32 tiled GEMM: 64x64 tile, BK=16, 256 threads, 4x4 per thread.
// ---------------------------------------------------------------------------
__global__ __launch_bounds__(256) void qkv_gemm_kernel(
    const float* __restrict__ x, const float* __restrict__ W,
    const float* __restrict__ bias,
    float* __restrict__ qb, float* __restrict__ kb, float* __restrict__ vb)
{
    __shared__ float As[16][65];   // [k][m], +1 pad
    __shared__ float Bs[16][65];   // [k][n]
    const int m0 = blockIdx.x * 64;
    const int n0 = blockIdx.y * 64;
    const int tid = threadIdx.x;
    const int tm = (tid >> 4) * 4;
    const int tn = (tid & 15) * 4;
    const int ak = tid & 15;   // k within A tile
    const int am = tid >> 4;   // row group
    const int bn = tid & 63;   // n within B tile
    const int bk = tid >> 6;   // k row group
    float acc[4][4] = {{0.f}};

    for (int k0 = 0; k0 < E_DIM; k0 += 16) {
        #pragma unroll
        for (int p = 0; p < 4; ++p) {
            As[ak][am + 16 * p] = x[(size_t)(m0 + am + 16 * p) * E_DIM + k0 + ak];
            Bs[bk + 4 * p][bn]  = W[(size_t)(k0 + bk + 4 * p) * QKV_N + n0 + bn];
        }
        __syncthreads();
        #pragma unroll
        for (int kk = 0; kk < 16; ++kk) {
            float a[4], b[4];
            #pragma unroll
            for (int i = 0; i < 4; ++i) a[i] = As[kk][tm + i];
            #pragma unroll
            for (int j = 0; j < 4; ++j) b[j] = Bs[kk][tn + j];
            #pragma unroll
            for (int i = 0; i < 4; ++i)
                #pragma unroll
                for (int j = 0; j < 4; ++j)
                    acc[i][j] = fmaf(a[i], b[j], acc[i][j]);
        }
        __syncthreads();
    }

    #pragma unroll
    for (int i = 0; i < 4; ++i) {
        const int m  = m0 + tm + i;
        const int bb = m >> 11;     // / L_DIM
        const int l  = m & 2047;
        #pragma unroll
        for (int j = 0; j < 4; ++j) {
            const int n = n0 + tn + j;
            const float v = acc[i][j] + bias[n];
            const int sel = n >> 10;          // 0=q 1=k 2=v
            const int h   = (n & 1023) >> 6;
            const int d   = n & 63;
            float* dst = (sel == 0) ? qb : (sel == 1) ? kb : vb;
            dst[((size_t)((bb * H_DIM + h) * L_DIM + l)) * HD + d] = v;
        }
    }
}

// ---------------------------------------------------------------------------
// K2: L2-normalize each row of [nrows][64] in place. One wave per row.
// ---------------------------------------------------------------------------
__global__ __launch_bounds__(256) void normalize_kernel(float* __restrict__ buf, int nrows)
{
    const int r = blockIdx.x * 4 + (threadIdx.x >> 6);
    const int lane = threadIdx.x & 63;
    if (r >= nrows) return;
    float v = buf[(size_t)r * HD + lane];
    float s = v * v;
    #pragma unroll
    for (int m = 1; m < 64; m <<= 1) s += __shfl_xor(s, m);
    buf[(size_t)r * HD + lane] = v * (1.0f / sqrtf(s));
}

// ---------------------------------------------------------------------------
// K3: causal attention, one wave per query row (lane = d). Online softmax.
// score = x^2 / (2.01 - 2x) on the cosine similarity x.
// ---------------------------------------------------------------------------
__global__ __launch_bounds__(256) void attn_kernel(
    const float* __restrict__ qb, const float* __restrict__ kb,
    const float* __restrict__ vb, float* __restrict__ ctx)
{
    const int r = blockIdx.x * 4 + (threadIdx.x >> 6);  // (b*16+h)*2048 + i
    const int lane = threadIdx.x & 63;
    const int bh = r >> 11;
    const int i  = r & 2047;
    const float q = qb[(size_t)r * HD + lane];
    const float* kbase = kb + ((size_t)bh * L_DIM) * HD;
    const float* vbase = vb + ((size_t)bh * L_DIM) * HD;

    float m = -1e30f, ssum = 0.f, o = 0.f;
    for (int j = 0; j <= i; ++j) {
        float d = q * kbase[(size_t)j * HD + lane];
        #pragma unroll
        for (int s = 1; s < 64; s <<= 1) d += __shfl_xor(d, s);
        const float score = d * d / (C_CONST - 2.f * d);
        const float nm = fmaxf(m, score);
        const float scale = __expf(m - nm);
        const float p = __expf(score - nm);
        ssum = ssum * scale + p;
        o = o * scale + p * vbase[(size_t)j * HD + lane];
        m = nm;
    }
    ctx[(size_t)r * HD + lane] = o / ssum;
}

// ---------------------------------------------------------------------------
// K4: out = ctx([B,H,L,D] gathered as [M=4096][K=1024]) @ W_out + b_out
// ---------------------------------------------------------------------------
__global__ __launch_bounds__(256) void out_gemm_kernel(
    const float* __restrict__ ctx, const float* __restrict__ W,
    const float* __restrict__ bias, float* __restrict__ out)
{
    __shared__ float As[16][65];
    __shared__ float Bs[16][65];
    const int m0 = blockIdx.x * 64;
    const int n0 = blockIdx.y * 64;
    const int tid = threadIdx.x;
    const int tm = (tid >> 4) * 4;
    const int tn = (tid & 15) * 4;
    const int ak = tid & 15;
    const int am = tid >> 4;
    const int bn = tid & 63;
    const int bk = tid >> 6;
    float acc[4][4] = {{0.f}};

    for (int k0 = 0; k0 < E_DIM; k0 += 16) {
        #pragma unroll
        for (int p = 0; p < 4; ++p) {
            const int m = m0 + am + 16 * p;
            const int k = k0 + ak;
            const int bb = m >> 11, l = m & 2047, h = k >> 6, d = k & 63;
            As[ak][am + 16 * p] = ctx[((size_t)((bb * H_DIM + h) * L_DIM + l)) * HD + d];
            Bs[bk + 4 * p][bn]  = W[(size_t)(k0 + bk + 4 * p) * E_DIM + n0 + bn];
        }
        __syncthreads();
        #pragma unroll
        for (int kk = 0; kk < 16; ++kk) {
            float a[4], b[4];
            #pragma unroll
            for (int i = 0; i < 4; ++i) a[i] = As[kk][tm + i];
            #pragma unroll
            for (int j = 0; j < 4; ++j) b[j] = Bs[kk][tn + j];
            #pragma unroll
            for (int i = 0; i < 4; ++i)
                #pragma unroll
                for (int j = 0; j < 4; ++j)
                    acc[i][j] = fmaf(a[i], b[j], acc[i][j]);
        }
        __syncthreads();
    }

    #pragma unroll
    for (int i = 0; i < 4; ++i) {
        const int m = m0 + tm + i;
        #pragma unroll
        for (int j = 0; j < 4; ++j) {
            const int n = n0 + tn + j;
            out[(size_t)m * E_DIM + n] = acc[i][j] + bias[n];
        }
    }
}

// ---------------------------------------------------------------------------
extern "C" void kernel_launch(void* const* d_in, const int* in_sizes, int n_in,
                              void* d_out, int out_size, void* d_ws, size_t ws_size,
                              hipStream_t stream)
{
    const float* x    = (const float*)d_in[0];
    const float* Wqkv = (const float*)d_in[1];
    const float* bqkv = (const float*)d_in[2];
    const float* Wout = (const float*)d_in[3];
    const float* bout = (const float*)d_in[4];
    float* out = (float*)d_out;

    const size_t seg = (size_t)B_DIM * H_DIM * L_DIM * HD;  // 4,194,304 floats
    float* qb  = (float*)d_ws;
    float* kb  = qb + seg;
    float* vb  = kb + seg;
    float* ctx = vb + seg;   // total 4*seg*4B = 67.1 MB scratch

    dim3 g1(M_ROWS / 64, QKV_N / 64);
    qkv_gemm_kernel<<<g1, 256, 0, stream>>>(x, Wqkv, bqkv, qb, kb, vb);

    const int nrows = B_DIM * H_DIM * L_DIM;  // 65536
    normalize_kernel<<<nrows / 4, 256, 0, stream>>>(qb, nrows);
    normalize_kernel<<<nrows / 4, 256, 0, stream>>>(kb, nrows);

    attn_kernel<<<nrows / 4, 256, 0, stream>>>(qb, kb, vb, ctx);

    dim3 g2(M_ROWS / 64, E_DIM / 64);
    out_gemm_kernel<<<g2, 256, 0, stream>>>(ctx, Wout, bout, out);
}

// Round 5
// 1268.479 us; speedup vs baseline: 4.3656x; 4.3656x over previous
//
#include <hip/hip_runtime.h>
#include <cstdint>
#include <cstddef>

// Problem dims (compile-time)
#define B_DIM 2
#define L_DIM 2048
#define E_DIM 1024
#define H_DIM 16
#define HD    64
#define M_ROWS (B_DIM * L_DIM)   // 4096
#define QKV_N  (3 * E_DIM)       // 3072
#define C_CONST 2.01f

// ---------------------------------------------------------------------------
// K1: qkv = x @ W_qkv + b_qkv, scattered directly into q/k/v [B,H,L,D] bufs.
// Classic fp32 tiled GEMM: 64x64 tile, BK=16, 256 threads, 4x4 per thread.
// ---------------------------------------------------------------------------
__global__ __launch_bounds__(256) void qkv_gemm_kernel(
    const float* __restrict__ x, const float* __restrict__ W,
    const float* __restrict__ bias,
    float* __restrict__ qb, float* __restrict__ kb, float* __restrict__ vb)
{
    __shared__ float As[16][65];   // [k][m], +1 pad
    __shared__ float Bs[16][65];   // [k][n]
    const int m0 = blockIdx.x * 64;
    const int n0 = blockIdx.y * 64;
    const int tid = threadIdx.x;
    const int tm = (tid >> 4) * 4;
    const int tn = (tid & 15) * 4;
    const int ak = tid & 15;   // k within A tile
    const int am = tid >> 4;   // row group
    const int bn = tid & 63;   // n within B tile
    const int bk = tid >> 6;   // k row group
    float acc[4][4] = {{0.f}};

    for (int k0 = 0; k0 < E_DIM; k0 += 16) {
        #pragma unroll
        for (int p = 0; p < 4; ++p) {
            As[ak][am + 16 * p] = x[(size_t)(m0 + am + 16 * p) * E_DIM + k0 + ak];
            Bs[bk + 4 * p][bn]  = W[(size_t)(k0 + bk + 4 * p) * QKV_N + n0 + bn];
        }
        __syncthreads();
        #pragma unroll
        for (int kk = 0; kk < 16; ++kk) {
            float a[4], b[4];
            #pragma unroll
            for (int i = 0; i < 4; ++i) a[i] = As[kk][tm + i];
            #pragma unroll
            for (int j = 0; j < 4; ++j) b[j] = Bs[kk][tn + j];
            #pragma unroll
            for (int i = 0; i < 4; ++i)
                #pragma unroll
                for (int j = 0; j < 4; ++j)
                    acc[i][j] = fmaf(a[i], b[j], acc[i][j]);
        }
        __syncthreads();
    }

    #pragma unroll
    for (int i = 0; i < 4; ++i) {
        const int m  = m0 + tm + i;
        const int bb = m >> 11;     // / L_DIM
        const int l  = m & 2047;
        #pragma unroll
        for (int j = 0; j < 4; ++j) {
            const int n = n0 + tn + j;
            const float v = acc[i][j] + bias[n];
            const int sel = n >> 10;          // 0=q 1=k 2=v
            const int h   = (n & 1023) >> 6;
            const int d   = n & 63;
            float* dst = (sel == 0) ? qb : (sel == 1) ? kb : vb;
            dst[((size_t)((bb * H_DIM + h) * L_DIM + l)) * HD + d] = v;
        }
    }
}

// ---------------------------------------------------------------------------
// K2: L2-normalize each row of [nrows][64] in place. One wave per row.
// ---------------------------------------------------------------------------
__global__ __launch_bounds__(256) void normalize_kernel(float* __restrict__ buf, int nrows)
{
    const int r = blockIdx.x * 4 + (threadIdx.x >> 6);
    const int lane = threadIdx.x & 63;
    if (r >= nrows) return;
    float v = buf[(size_t)r * HD + lane];
    float s = v * v;
    #pragma unroll
    for (int m = 1; m < 64; m <<= 1) s += __shfl_xor(s, m);
    buf[(size_t)r * HD + lane] = v * (1.0f / sqrtf(s));
}

// ---------------------------------------------------------------------------
// K3: tiled flash attention, fp32. One block per (qblock=64 rows, bh).
// 256 threads as 16x16 grid, 4x4 register tile each. Two 64^3 register GEMMs
// per key tile (S = Qn.Kn^T, O += P.V) with online softmax between them.
// score = x^2 / (2.01 - 2x), causal mask on the diagonal tile only.
// ---------------------------------------------------------------------------
__global__ __launch_bounds__(256) void attn_kernel(
    const float* __restrict__ qn, const float* __restrict__ kn,
    const float* __restrict__ vv, float* __restrict__ ctx)
{
    __shared__ float Qs[64][68];   // [d][r]  (transposed)
    __shared__ float Ks[64][68];   // [d][c]  (transposed)
    __shared__ float Vs[64][68];   // [c][d]  (row-major)
    __shared__ float Ps[64][68];   // [c][r]  (transposed)

    const int bh = blockIdx.y;          // 0..31 (b*16+h)
    const int qblk = blockIdx.x;        // 0..31
    const int q0 = qblk * 64;
    const int tid = threadIdx.x;
    const int tm = tid >> 4;            // 0..15 -> rows 4tm..4tm+3
    const int tn = tid & 15;            // 0..15 -> cols 4tn..4tn+3

    const float* Qg = qn + ((size_t)bh * L_DIM + q0) * HD;
    const float* Kg = kn + (size_t)bh * L_DIM * HD;
    const float* Vg = vv + (size_t)bh * L_DIM * HD;

    // stage Q tile (transposed)
    for (int idx = tid; idx < 64 * 64; idx += 256) {
        const int r = idx >> 6, d = idx & 63;
        Qs[d][r] = Qg[(size_t)r * HD + d];
    }

    float m_i[4], l_i[4], acc[4][4];
    #pragma unroll
    for (int i = 0; i < 4; ++i) {
        m_i[i] = -1e30f; l_i[i] = 0.f;
        #pragma unroll
        for (int j = 0; j < 4; ++j) acc[i][j] = 0.f;
    }

    for (int kt = 0; kt <= qblk; ++kt) {
        const int j0 = kt * 64;
        __syncthreads();   // previous PV done (and Q staged, first iter)
        for (int idx = tid; idx < 64 * 64; idx += 256) {
            const int c = idx >> 6, d = idx & 63;
            const float kvv = Kg[(size_t)(j0 + c) * HD + d];
            Ks[d][c] = kvv;
            Vs[c][d] = Vg[(size_t)(j0 + c) * HD + d];
        }
        __syncthreads();

        // ---- S = Q . K^T  (4x4 per thread over kk=d) ----
        float s[4][4] = {{0.f}};
        #pragma unroll 4
        for (int kk = 0; kk < 64; ++kk) {
            const float4 av = *(const float4*)&Qs[kk][tm * 4];
            const float4 bv = *(const float4*)&Ks[kk][tn * 4];
            const float a[4] = {av.x, av.y, av.z, av.w};
            const float b[4] = {bv.x, bv.y, bv.z, bv.w};
            #pragma unroll
            for (int i = 0; i < 4; ++i)
                #pragma unroll
                for (int j = 0; j < 4; ++j)
                    s[i][j] = fmaf(a[i], b[j], s[i][j]);
        }

        // ---- score transform + causal mask + online softmax ----
        const bool diag = (kt == qblk);
        float p[4][4];
        #pragma unroll
        for (int i = 0; i < 4; ++i) {
            const int gr = q0 + tm * 4 + i;
            float rowmax = -1e30f;
            #pragma unroll
            for (int j = 0; j < 4; ++j) {
                const float x = s[i][j];
                float sc = __fdividef(x * x, C_CONST - 2.f * x);
                if (diag && (j0 + tn * 4 + j) > gr) sc = -1e30f;
                s[i][j] = sc;
                rowmax = fmaxf(rowmax, sc);
            }
            #pragma unroll
            for (int w = 1; w < 16; w <<= 1)
                rowmax = fmaxf(rowmax, __shfl_xor(rowmax, w));
            const float newm = fmaxf(m_i[i], rowmax);
            const float scl = __expf(m_i[i] - newm);
            m_i[i] = newm;
            float tsum = 0.f;
            #pragma unroll
            for (int j = 0; j < 4; ++j) {
                const float pv = __expf(s[i][j] - newm);
                p[i][j] = pv;
                tsum += pv;
            }
            #pragma unroll
            for (int w = 1; w < 16; w <<= 1) tsum += __shfl_xor(tsum, w);
            l_i[i] = l_i[i] * scl + tsum;
            #pragma unroll
            for (int j = 0; j < 4; ++j) acc[i][j] *= scl;
        }

        // stage P transposed: Ps[c][r]
        #pragma unroll
        for (int j = 0; j < 4; ++j) {
            const float4 w4 = make_float4(p[0][j], p[1][j], p[2][j], p[3][j]);
            *(float4*)&Ps[tn * 4 + j][tm * 4] = w4;
        }
        __syncthreads();

        // ---- O += P . V  (kk over key index c) ----
        #pragma unroll 4
        for (int c = 0; c < 64; ++c) {
            const float4 av = *(const float4*)&Ps[c][tm * 4];
            const float4 bv = *(const float4*)&Vs[c][tn * 4];
            const float a[4] = {av.x, av.y, av.z, av.w};
            const float b[4] = {bv.x, bv.y, bv.z, bv.w};
            #pragma unroll
            for (int i = 0; i < 4; ++i)
                #pragma unroll
                for (int j = 0; j < 4; ++j)
                    acc[i][j] = fmaf(a[i], b[j], acc[i][j]);
        }
    }

    // epilogue: divide by l and store
    float* Og = ctx + ((size_t)bh * L_DIM + q0) * HD;
    #pragma unroll
    for (int i = 0; i < 4; ++i) {
        const float inv = 1.0f / l_i[i];
        const float4 o = make_float4(acc[i][0] * inv, acc[i][1] * inv,
                                     acc[i][2] * inv, acc[i][3] * inv);
        *(float4*)&Og[(size_t)(tm * 4 + i) * HD + tn * 4] = o;
    }
}

// ---------------------------------------------------------------------------
// K4: out = ctx([B,H,L,D] gathered as [M=4096][K=1024]) @ W_out + b_out
// ---------------------------------------------------------------------------
__global__ __launch_bounds__(256) void out_gemm_kernel(
    const float* __restrict__ ctx, const float* __restrict__ W,
    const float* __restrict__ bias, float* __restrict__ out)
{
    __shared__ float As[16][65];
    __shared__ float Bs[16][65];
    const int m0 = blockIdx.x * 64;
    const int n0 = blockIdx.y * 64;
    const int tid = threadIdx.x;
    const int tm = (tid >> 4) * 4;
    const int tn = (tid & 15) * 4;
    const int ak = tid & 15;
    const int am = tid >> 4;
    const int bn = tid & 63;
    const int bk = tid >> 6;
    float acc[4][4] = {{0.f}};

    for (int k0 = 0; k0 < E_DIM; k0 += 16) {
        #pragma unroll
        for (int p = 0; p < 4; ++p) {
            const int m = m0 + am + 16 * p;
            const int k = k0 + ak;
            const int bb = m >> 11, l = m & 2047, h = k >> 6, d = k & 63;
            As[ak][am + 16 * p] = ctx[((size_t)((bb * H_DIM + h) * L_DIM + l)) * HD + d];
            Bs[bk + 4 * p][bn]  = W[(size_t)(k0 + bk + 4 * p) * E_DIM + n0 + bn];
        }
        __syncthreads();
        #pragma unroll
        for (int kk = 0; kk < 16; ++kk) {
            float a[4], b[4];
            #pragma unroll
            for (int i = 0; i < 4; ++i) a[i] = As[kk][tm + i];
            #pragma unroll
            for (int j = 0; j < 4; ++j) b[j] = Bs[kk][tn + j];
            #pragma unroll
            for (int i = 0; i < 4; ++i)
                #pragma unroll
                for (int j = 0; j < 4; ++j)
                    acc[i][j] = fmaf(a[i], b[j], acc[i][j]);
        }
        __syncthreads();
    }

    #pragma unroll
    for (int i = 0; i < 4; ++i) {
        const int m = m0 + tm + i;
        #pragma unroll
        for (int j = 0; j < 4; ++j) {
            const int n = n0 + tn + j;
            out[(size_t)m * E_DIM + n] = acc[i][j] + bias[n];
        }
    }
}

// ---------------------------------------------------------------------------
extern "C" void kernel_launch(void* const* d_in, const int* in_sizes, int n_in,
                              void* d_out, int out_size, void* d_ws, size_t ws_size,
                              hipStream_t stream)
{
    const float* x    = (const float*)d_in[0];
    const float* Wqkv = (const float*)d_in[1];
    const float* bqkv = (const float*)d_in[2];
    const float* Wout = (const float*)d_in[3];
    const float* bout = (const float*)d_in[4];
    float* out = (float*)d_out;

    const size_t seg = (size_t)B_DIM * H_DIM * L_DIM * HD;  // 4,194,304 floats
    float* qb  = (float*)d_ws;
    float* kb  = qb + seg;
    float* vb  = kb + seg;
    float* ctx = vb + seg;   // total 4*seg*4B = 67.1 MB scratch

    dim3 g1(M_ROWS / 64, QKV_N / 64);
    qkv_gemm_kernel<<<g1, 256, 0, stream>>>(x, Wqkv, bqkv, qb, kb, vb);

    const int nrows = B_DIM * H_DIM * L_DIM;  // 65536
    normalize_kernel<<<nrows / 4, 256, 0, stream>>>(qb, nrows);
    normalize_kernel<<<nrows / 4, 256, 0, stream>>>(kb, nrows);

    dim3 ga(L_DIM / 64, B_DIM * H_DIM);   // (32 qblocks, 32 bh)
    attn_kernel<<<ga, 256, 0, stream>>>(qb, kb, vb, ctx);

    dim3 g2(M_ROWS / 64, E_DIM / 64);
    out_gemm_kernel<<<g2, 256, 0, stream>>>(ctx, Wout, bout, out);
}

// Round 6
// 699.523 us; speedup vs baseline: 7.9164x; 1.8133x over previous
//
#include <hip/hip_runtime.h>
#include <cstdint>
#include <cstddef>

// Problem dims (compile-time)
#define B_DIM 2
#define L_DIM 2048
#define E_DIM 1024
#define H_DIM 16
#define HD    64
#define M_ROWS (B_DIM * L_DIM)   // 4096
#define QKV_N  (3 * E_DIM)       // 3072
#define C_CONST 2.01f

typedef __attribute__((ext_vector_type(8))) short bf16x8;
typedef __attribute__((ext_vector_type(4))) float f32x4;

__device__ __forceinline__ unsigned int f2bf(float f) {
    union { float f; unsigned int u; } v; v.f = f;
    return (v.u + 0x7FFFu + ((v.u >> 16) & 1u)) >> 16;   // RNE
}

__device__ __forceinline__ void gload16(const void* g, void* l) {
    __builtin_amdgcn_global_load_lds(
        (const __attribute__((address_space(1))) void*)g,
        (__attribute__((address_space(3))) void*)l, 16, 0, 0);
}

// ---------------------------------------------------------------------------
// cast fp32 -> bf16 (contiguous), 4 elems/thread
// ---------------------------------------------------------------------------
__global__ __launch_bounds__(256) void cast_bf16_kernel(
    const float* __restrict__ in, unsigned short* __restrict__ out, int n4)
{
    const int i = blockIdx.x * 256 + threadIdx.x;
    if (i >= n4) return;
    const float4 v = ((const float4*)in)[i];
    uint2 p;
    p.x = f2bf(v.x) | (f2bf(v.y) << 16);
    p.y = f2bf(v.z) | (f2bf(v.w) << 16);
    ((uint2*)out)[i] = p;
}

// ---------------------------------------------------------------------------
// transpose fp32 [R][Cn] -> bf16 [Cn][R]
// ---------------------------------------------------------------------------
__global__ __launch_bounds__(256) void transpose_bf16_kernel(
    const float* __restrict__ in, unsigned short* __restrict__ out, int R, int Cn)
{
    __shared__ float t[64][65];
    const int c0 = blockIdx.x * 64, r0 = blockIdx.y * 64;
    const int tid = threadIdx.x;
    for (int idx = tid; idx < 4096; idx += 256) {
        const int r = idx >> 6, c = idx & 63;
        t[r][c] = in[(size_t)(r0 + r) * Cn + c0 + c];
    }
    __syncthreads();
    for (int idx = tid; idx < 4096; idx += 256) {
        const int c = idx >> 6, r = idx & 63;
        out[(size_t)(c0 + c) * R + r0 + r] = (unsigned short)f2bf(t[r][c]);
    }
}

// ---------------------------------------------------------------------------
// gather ctx [bh][l][d] fp32 -> cb [m=b*2048+l][e=h*64+d] bf16
// ---------------------------------------------------------------------------
__global__ __launch_bounds__(256) void gather_ctx_kernel(
    const float* __restrict__ ctx, unsigned short* __restrict__ cb)
{
    const int gid = blockIdx.x * 256 + threadIdx.x;   // 1M threads, 4 elems each
    const int m = gid >> 8, e4 = gid & 255;
    const int b = m >> 11, l = m & 2047;
    const int h = e4 >> 4, d = (e4 & 15) * 4;
    const float4 v = *(const float4*)&ctx[(((size_t)(b * H_DIM + h) * L_DIM + l) * HD + d)];
    uint2 p;
    p.x = f2bf(v.x) | (f2bf(v.y) << 16);
    p.y = f2bf(v.z) | (f2bf(v.w) << 16);
    ((uint2*)cb)[gid] = p;
}

// ---------------------------------------------------------------------------
// bf16 MFMA GEMM, m97-style: 128x128 tile, BK=32, 4 waves, 64x64 per wave.
// A [4096][1024] bf16 row-major; BT [NCOLS][1024] bf16 (B transposed).
// MODE 0: scatter qkv (+bias) into q/k/v [B,H,L,D] fp32.  MODE 1: plain C+bias.
// ---------------------------------------------------------------------------
template<int NCOLS, int MODE>
__global__ __launch_bounds__(256) void gemm_bt_kernel(
    const unsigned short* __restrict__ A, const unsigned short* __restrict__ BT,
    const float* __restrict__ bias,
    float* __restrict__ d0, float* __restrict__ d1, float* __restrict__ d2)
{
    __shared__ __align__(16) unsigned short Abuf[128 * 32];
    __shared__ __align__(16) unsigned short Bbuf[128 * 32];
    const int tid = threadIdx.x;
    const int wave = tid >> 6, lane = tid & 63;
    const int m0 = blockIdx.x * 128, n0 = blockIdx.y * 128;
    const int wr = (wave >> 1) * 64, wc = (wave & 1) * 64;
    const int g = lane >> 4, l15 = lane & 15;

    f32x4 acc[4][4];
    #pragma unroll
    for (int i = 0; i < 4; ++i)
        #pragma unroll
        for (int j = 0; j < 4; ++j) acc[i][j] = f32x4{0.f, 0.f, 0.f, 0.f};

    const int sr = tid >> 2;           // staging row 0..63
    const int sc = (tid & 3) * 8;      // staging col (elements)
    const unsigned short* Asrc0 = A + (size_t)(m0 + sr) * 1024 + sc;
    const unsigned short* Asrc1 = A + (size_t)(m0 + 64 + sr) * 1024 + sc;
    const unsigned short* Bsrc0 = BT + (size_t)(n0 + sr) * 1024 + sc;
    const unsigned short* Bsrc1 = BT + (size_t)(n0 + 64 + sr) * 1024 + sc;
    unsigned short* Adst0 = &Abuf[tid * 8];
    unsigned short* Adst1 = &Abuf[2048 + tid * 8];
    unsigned short* Bdst0 = &Bbuf[tid * 8];
    unsigned short* Bdst1 = &Bbuf[2048 + tid * 8];

    for (int k0 = 0; k0 < 1024; k0 += 32) {
        __syncthreads();                   // prior reads done
        gload16(Asrc0 + k0, Adst0);
        gload16(Asrc1 + k0, Adst1);
        gload16(Bsrc0 + k0, Bdst0);
        gload16(Bsrc1 + k0, Bdst1);
        __syncthreads();                   // staging drained (vmcnt 0 at barrier)

        bf16x8 af[4];
        #pragma unroll
        for (int mt = 0; mt < 4; ++mt)
            af[mt] = *(const bf16x8*)&Abuf[(wr + mt * 16 + l15) * 32 + 8 * g];
        #pragma unroll
        for (int nt = 0; nt < 4; ++nt) {
            const bf16x8 bfr = *(const bf16x8*)&Bbuf[(wc + nt * 16 + l15) * 32 + 8 * g];
            #pragma unroll
            for (int mt = 0; mt < 4; ++mt)
                acc[mt][nt] = __builtin_amdgcn_mfma_f32_16x16x32_bf16(af[mt], bfr, acc[mt][nt], 0, 0, 0);
        }
    }

    // epilogue: D[row=4*g+r][col=l15] per 16x16 tile (m89-verified layout)
    #pragma unroll
    for (int nt = 0; nt < 4; ++nt) {
        const int n = n0 + wc + nt * 16 + l15;
        const float bv = bias[n];
        if (MODE == 0) {
            const int sel = n >> 10, h = (n & 1023) >> 6, d = n & 63;
            float* dst = (sel == 0) ? d0 : (sel == 1) ? d1 : d2;
            #pragma unroll
            for (int mt = 0; mt < 4; ++mt) {
                #pragma unroll
                for (int r = 0; r < 4; ++r) {
                    const int m = m0 + wr + mt * 16 + 4 * g + r;
                    const int bb = m >> 11, ll = m & 2047;
                    dst[((size_t)((bb * H_DIM + h) * L_DIM + ll)) * HD + d] = acc[mt][nt][r] + bv;
                }
            }
        } else {
            #pragma unroll
            for (int mt = 0; mt < 4; ++mt) {
                #pragma unroll
                for (int r = 0; r < 4; ++r) {
                    const int m = m0 + wr + mt * 16 + 4 * g + r;
                    d0[(size_t)m * E_DIM + n] = acc[mt][nt][r] + bv;
                }
            }
        }
    }
}

// ---------------------------------------------------------------------------
// K2: L2-normalize each row of [nrows][64] in place. One wave per row.
// ---------------------------------------------------------------------------
__global__ __launch_bounds__(256) void normalize_kernel(float* __restrict__ buf, int nrows)
{
    const int r = blockIdx.x * 4 + (threadIdx.x >> 6);
    const int lane = threadIdx.x & 63;
    if (r >= nrows) return;
    float v = buf[(size_t)r * HD + lane];
    float s = v * v;
    #pragma unroll
    for (int m = 1; m < 64; m <<= 1) s += __shfl_xor(s, m);
    buf[(size_t)r * HD + lane] = v * (1.0f / sqrtf(s));
}

// ---------------------------------------------------------------------------
// K3: tiled flash attention, fp32 (unchanged from round 5 measured version).
// ---------------------------------------------------------------------------
__global__ __launch_bounds__(256) void attn_kernel(
    const float* __restrict__ qn, const float* __restrict__ kn,
    const float* __restrict__ vv, float* __restrict__ ctx)
{
    __shared__ float Qs[64][68];   // [d][r]
    __shared__ float Ks[64][68];   // [d][c]
    __shared__ float Vs[64][68];   // [c][d]
    __shared__ float Ps[64][68];   // [c][r]

    const int bh = blockIdx.y;
    const int qblk = blockIdx.x;
    const int q0 = qblk * 64;
    const int tid = threadIdx.x;
    const int tm = tid >> 4;
    const int tn = tid & 15;

    const float* Qg = qn + ((size_t)bh * L_DIM + q0) * HD;
    const float* Kg = kn + (size_t)bh * L_DIM * HD;
    const float* Vg = vv + (size_t)bh * L_DIM * HD;

    for (int idx = tid; idx < 64 * 64; idx += 256) {
        const int r = idx >> 6, d = idx & 63;
        Qs[d][r] = Qg[(size_t)r * HD + d];
    }

    float m_i[4], l_i[4], acc[4][4];
    #pragma unroll
    for (int i = 0; i < 4; ++i) {
        m_i[i] = -1e30f; l_i[i] = 0.f;
        #pragma unroll
        for (int j = 0; j < 4; ++j) acc[i][j] = 0.f;
    }

    for (int kt = 0; kt <= qblk; ++kt) {
        const int j0 = kt * 64;
        __syncthreads();
        for (int idx = tid; idx < 64 * 64; idx += 256) {
            const int c = idx >> 6, d = idx & 63;
            Ks[d][c] = Kg[(size_t)(j0 + c) * HD + d];
            Vs[c][d] = Vg[(size_t)(j0 + c) * HD + d];
        }
        __syncthreads();

        float s[4][4] = {{0.f}};
        #pragma unroll 4
        for (int kk = 0; kk < 64; ++kk) {
            const float4 av = *(const float4*)&Qs[kk][tm * 4];
            const float4 bv = *(const float4*)&Ks[kk][tn * 4];
            const float a[4] = {av.x, av.y, av.z, av.w};
            const float b[4] = {bv.x, bv.y, bv.z, bv.w};
            #pragma unroll
            for (int i = 0; i < 4; ++i)
                #pragma unroll
                for (int j = 0; j < 4; ++j)
                    s[i][j] = fmaf(a[i], b[j], s[i][j]);
        }

        const bool diag = (kt == qblk);
        float p[4][4];
        #pragma unroll
        for (int i = 0; i < 4; ++i) {
            const int gr = q0 + tm * 4 + i;
            float rowmax = -1e30f;
            #pragma unroll
            for (int j = 0; j < 4; ++j) {
                const float x = s[i][j];
                float sc = __fdividef(x * x, C_CONST - 2.f * x);
                if (diag && (j0 + tn * 4 + j) > gr) sc = -1e30f;
                s[i][j] = sc;
                rowmax = fmaxf(rowmax, sc);
            }
            #pragma unroll
            for (int w = 1; w < 16; w <<= 1)
                rowmax = fmaxf(rowmax, __shfl_xor(rowmax, w));
            const float newm = fmaxf(m_i[i], rowmax);
            const float scl = __expf(m_i[i] - newm);
            m_i[i] = newm;
            float tsum = 0.f;
            #pragma unroll
            for (int j = 0; j < 4; ++j) {
                const float pv = __expf(s[i][j] - newm);
                p[i][j] = pv;
                tsum += pv;
            }
            #pragma unroll
            for (int w = 1; w < 16; w <<= 1) tsum += __shfl_xor(tsum, w);
            l_i[i] = l_i[i] * scl + tsum;
            #pragma unroll
            for (int j = 0; j < 4; ++j) acc[i][j] *= scl;
        }

        #pragma unroll
        for (int j = 0; j < 4; ++j) {
            const float4 w4 = make_float4(p[0][j], p[1][j], p[2][j], p[3][j]);
            *(float4*)&Ps[tn * 4 + j][tm * 4] = w4;
        }
        __syncthreads();

        #pragma unroll 4
        for (int c = 0; c < 64; ++c) {
            const float4 av = *(const float4*)&Ps[c][tm * 4];
            const float4 bv = *(const float4*)&Vs[c][tn * 4];
            const float a[4] = {av.x, av.y, av.z, av.w};
            const float b[4] = {bv.x, bv.y, bv.z, bv.w};
            #pragma unroll
            for (int i = 0; i < 4; ++i)
                #pragma unroll
                for (int j = 0; j < 4; ++j)
                    acc[i][j] = fmaf(a[i], b[j], acc[i][j]);
        }
    }

    float* Og = ctx + ((size_t)bh * L_DIM + q0) * HD;
    #pragma unroll
    for (int i = 0; i < 4; ++i) {
        const float inv = 1.0f / l_i[i];
        const float4 o = make_float4(acc[i][0] * inv, acc[i][1] * inv,
                                     acc[i][2] * inv, acc[i][3] * inv);
        *(float4*)&Og[(size_t)(tm * 4 + i) * HD + tn * 4] = o;
    }
}

// ---------------------------------------------------------------------------
extern "C" void kernel_launch(void* const* d_in, const int* in_sizes, int n_in,
                              void* d_out, int out_size, void* d_ws, size_t ws_size,
                              hipStream_t stream)
{
    const float* x    = (const float*)d_in[0];
    const float* Wqkv = (const float*)d_in[1];
    const float* bqkv = (const float*)d_in[2];
    const float* Wout = (const float*)d_in[3];
    const float* bout = (const float*)d_in[4];
    float* out = (float*)d_out;

    const size_t seg = (size_t)B_DIM * H_DIM * L_DIM * HD;  // 4,194,304 floats
    float* qb  = (float*)d_ws;
    float* kb  = qb + seg;
    float* vb  = kb + seg;
    float* ctx = vb + seg;                 // total 4*seg*4B = 67.1 MB scratch
    // bf16 scratch overlapped into dead slots (lifetimes verified):
    unsigned short* xb    = (unsigned short*)ctx;                     // dead before attn writes ctx
    unsigned short* WqkvT = (unsigned short*)(ctx + 2 * 1024 * 1024); // dead before attn
    unsigned short* cb    = (unsigned short*)kb;                      // kb dead after attn
    unsigned short* WoutT = (unsigned short*)qb;                      // qb dead after attn

    // 1) bf16 copies for the qkv GEMM
    cast_bf16_kernel<<<4096, 256, 0, stream>>>(x, xb, (M_ROWS * E_DIM) / 4);
    transpose_bf16_kernel<<<dim3(QKV_N / 64, E_DIM / 64), 256, 0, stream>>>(Wqkv, WqkvT, E_DIM, QKV_N);

    // 2) qkv = x @ W_qkv + b (MFMA), scatter into q/k/v
    gemm_bt_kernel<QKV_N, 0><<<dim3(M_ROWS / 128, QKV_N / 128), 256, 0, stream>>>(
        xb, WqkvT, bqkv, qb, kb, vb);

    // 3) normalize q, k
    const int nrows = B_DIM * H_DIM * L_DIM;  // 65536
    normalize_kernel<<<nrows / 4, 256, 0, stream>>>(qb, nrows);
    normalize_kernel<<<nrows / 4, 256, 0, stream>>>(kb, nrows);

    // 4) attention (fp32, unchanged)
    dim3 ga(L_DIM / 64, B_DIM * H_DIM);
    attn_kernel<<<ga, 256, 0, stream>>>(qb, kb, vb, ctx);

    // 5) gather ctx -> bf16 [M][E]; transpose W_out
    gather_ctx_kernel<<<4096, 256, 0, stream>>>(ctx, cb);
    transpose_bf16_kernel<<<dim3(E_DIM / 64, E_DIM / 64), 256, 0, stream>>>(Wout, WoutT, E_DIM, E_DIM);

    // 6) out = ctx @ W_out + b (MFMA)
    gemm_bt_kernel<E_DIM, 1><<<dim3(M_ROWS / 128, E_DIM / 128), 256, 0, stream>>>(
        cb, WoutT, bout, out, nullptr, nullptr);
}

// Round 7
// 240.392 us; speedup vs baseline: 23.0363x; 2.9099x over previous
//
#include <hip/hip_runtime.h>
#include <cstdint>
#include <cstddef>

// Problem dims (compile-time)
#define B_DIM 2
#define L_DIM 2048
#define E_DIM 1024
#define H_DIM 16
#define HD    64
#define M_ROWS (B_DIM * L_DIM)   // 4096
#define QKV_N  (3 * E_DIM)       // 3072
#define C_CONST 2.01f

typedef unsigned short ushort_t;
typedef __attribute__((ext_vector_type(8))) short bf16x8;
typedef __attribute__((ext_vector_type(4))) float f32x4;

__device__ __forceinline__ unsigned int f2bf(float f) {
    union { float f; unsigned int u; } v; v.f = f;
    return (v.u + 0x7FFFu + ((v.u >> 16) & 1u)) >> 16;   // RNE
}

__device__ __forceinline__ void gload16(const void* g, void* l) {
    __builtin_amdgcn_global_load_lds(
        (const __attribute__((address_space(1))) void*)g,
        (__attribute__((address_space(3))) void*)l, 16, 0, 0);
}

// ---------------------------------------------------------------------------
// cast fp32 -> bf16 (contiguous), 4 elems/thread
// ---------------------------------------------------------------------------
__global__ __launch_bounds__(256) void cast_bf16_kernel(
    const float* __restrict__ in, ushort_t* __restrict__ out, int n4)
{
    const int i = blockIdx.x * 256 + threadIdx.x;
    if (i >= n4) return;
    const float4 v = ((const float4*)in)[i];
    uint2 p;
    p.x = f2bf(v.x) | (f2bf(v.y) << 16);
    p.y = f2bf(v.z) | (f2bf(v.w) << 16);
    ((uint2*)out)[i] = p;
}

// ---------------------------------------------------------------------------
// transpose fp32 [R][Cn] -> bf16 [Cn][R]
// ---------------------------------------------------------------------------
__global__ __launch_bounds__(256) void transpose_bf16_kernel(
    const float* __restrict__ in, ushort_t* __restrict__ out, int R, int Cn)
{
    __shared__ float t[64][65];
    const int c0 = blockIdx.x * 64, r0 = blockIdx.y * 64;
    const int tid = threadIdx.x;
    for (int idx = tid; idx < 4096; idx += 256) {
        const int r = idx >> 6, c = idx & 63;
        t[r][c] = in[(size_t)(r0 + r) * Cn + c0 + c];
    }
    __syncthreads();
    for (int idx = tid; idx < 4096; idx += 256) {
        const int c = idx >> 6, r = idx & 63;
        out[(size_t)(c0 + c) * R + r0 + r] = (ushort_t)f2bf(t[r][c]);
    }
}

// ---------------------------------------------------------------------------
// gather ctx [bh][l][d] fp32 -> cb [m=b*2048+l][e=h*64+d] bf16
// ---------------------------------------------------------------------------
__global__ __launch_bounds__(256) void gather_ctx_kernel(
    const float* __restrict__ ctx, ushort_t* __restrict__ cb)
{
    const int gid = blockIdx.x * 256 + threadIdx.x;
    const int m = gid >> 8, e4 = gid & 255;
    const int b = m >> 11, l = m & 2047;
    const int h = e4 >> 4, d = (e4 & 15) * 4;
    const float4 v = *(const float4*)&ctx[(((size_t)(b * H_DIM + h) * L_DIM + l) * HD + d)];
    uint2 p;
    p.x = f2bf(v.x) | (f2bf(v.y) << 16);
    p.y = f2bf(v.z) | (f2bf(v.w) << 16);
    ((uint2*)cb)[gid] = p;
}

// ---------------------------------------------------------------------------
// bf16 MFMA GEMM, 128x128 tile, BK=32, 4 waves. MODE 0: scatter q,k fp32 and
// v bf16 into [B,H,L,D] bufs. MODE 1: plain C+bias fp32.
// ---------------------------------------------------------------------------
template<int NCOLS, int MODE>
__global__ __launch_bounds__(256) void gemm_bt_kernel(
    const ushort_t* __restrict__ A, const ushort_t* __restrict__ BT,
    const float* __restrict__ bias,
    float* __restrict__ d0, float* __restrict__ d1, ushort_t* __restrict__ d2)
{
    __shared__ __align__(16) ushort_t Abuf[128 * 32];
    __shared__ __align__(16) ushort_t Bbuf[128 * 32];
    const int tid = threadIdx.x;
    const int wave = tid >> 6, lane = tid & 63;
    const int m0 = blockIdx.x * 128, n0 = blockIdx.y * 128;
    const int wr = (wave >> 1) * 64, wc = (wave & 1) * 64;
    const int g = lane >> 4, l15 = lane & 15;

    f32x4 acc[4][4];
    #pragma unroll
    for (int i = 0; i < 4; ++i)
        #pragma unroll
        for (int j = 0; j < 4; ++j) acc[i][j] = f32x4{0.f, 0.f, 0.f, 0.f};

    const int sr = tid >> 2;
    const int sc = (tid & 3) * 8;
    const ushort_t* Asrc0 = A + (size_t)(m0 + sr) * 1024 + sc;
    const ushort_t* Asrc1 = A + (size_t)(m0 + 64 + sr) * 1024 + sc;
    const ushort_t* Bsrc0 = BT + (size_t)(n0 + sr) * 1024 + sc;
    const ushort_t* Bsrc1 = BT + (size_t)(n0 + 64 + sr) * 1024 + sc;
    ushort_t* Adst0 = &Abuf[tid * 8];
    ushort_t* Adst1 = &Abuf[2048 + tid * 8];
    ushort_t* Bdst0 = &Bbuf[tid * 8];
    ushort_t* Bdst1 = &Bbuf[2048 + tid * 8];

    for (int k0 = 0; k0 < 1024; k0 += 32) {
        __syncthreads();
        gload16(Asrc0 + k0, Adst0);
        gload16(Asrc1 + k0, Adst1);
        gload16(Bsrc0 + k0, Bdst0);
        gload16(Bsrc1 + k0, Bdst1);
        __syncthreads();

        bf16x8 af[4];
        #pragma unroll
        for (int mt = 0; mt < 4; ++mt)
            af[mt] = *(const bf16x8*)&Abuf[(wr + mt * 16 + l15) * 32 + 8 * g];
        #pragma unroll
        for (int nt = 0; nt < 4; ++nt) {
            const bf16x8 bfr = *(const bf16x8*)&Bbuf[(wc + nt * 16 + l15) * 32 + 8 * g];
            #pragma unroll
            for (int mt = 0; mt < 4; ++mt)
                acc[mt][nt] = __builtin_amdgcn_mfma_f32_16x16x32_bf16(af[mt], bfr, acc[mt][nt], 0, 0, 0);
        }
    }

    #pragma unroll
    for (int nt = 0; nt < 4; ++nt) {
        const int n = n0 + wc + nt * 16 + l15;
        const float bv = bias[n];
        if (MODE == 0) {
            const int sel = n >> 10, h = (n & 1023) >> 6, d = n & 63;
            #pragma unroll
            for (int mt = 0; mt < 4; ++mt) {
                #pragma unroll
                for (int r = 0; r < 4; ++r) {
                    const int m = m0 + wr + mt * 16 + 4 * g + r;
                    const int bb = m >> 11, ll = m & 2047;
                    const size_t idx = ((size_t)((bb * H_DIM + h) * L_DIM + ll)) * HD + d;
                    const float val = acc[mt][nt][r] + bv;
                    if (sel == 0)      d0[idx] = val;
                    else if (sel == 1) d1[idx] = val;
                    else               d2[idx] = (ushort_t)f2bf(val);
                }
            }
        } else {
            #pragma unroll
            for (int mt = 0; mt < 4; ++mt) {
                #pragma unroll
                for (int r = 0; r < 4; ++r) {
                    const int m = m0 + wr + mt * 16 + 4 * g + r;
                    d0[(size_t)m * E_DIM + n] = acc[mt][nt][r] + bv;
                }
            }
        }
    }
}

// ---------------------------------------------------------------------------
// L2-normalize rows of fp32 [nrows][64], write bf16.
// ---------------------------------------------------------------------------
__global__ __launch_bounds__(256) void normalize_bf16_kernel(
    const float* __restrict__ in, ushort_t* __restrict__ out)
{
    const int r = blockIdx.x * 4 + (threadIdx.x >> 6);
    const int lane = threadIdx.x & 63;
    float v = in[(size_t)r * HD + lane];
    float s = v * v;
    #pragma unroll
    for (int m = 1; m < 64; m <<= 1) s += __shfl_xor(s, m);
    out[(size_t)r * HD + lane] = (ushort_t)f2bf(v * (1.0f / sqrtf(s)));
}

// ---------------------------------------------------------------------------
// transpose vb16 [bh][key][64] -> vt16 [bh][d][2048]
// ---------------------------------------------------------------------------
__global__ __launch_bounds__(256) void vt_transpose_kernel(
    const ushort_t* __restrict__ vb, ushort_t* __restrict__ vt)
{
    __shared__ ushort_t t[64][68];
    const int kt = blockIdx.x, bh = blockIdx.y;
    const int tid = threadIdx.x;
    const ushort_t* src = vb + ((size_t)bh * L_DIM + kt * 64) * HD;
    #pragma unroll
    for (int p = 0; p < 16; ++p) {
        const int idx = tid + 256 * p;
        t[idx >> 6][idx & 63] = src[idx];
    }
    __syncthreads();
    ushort_t* dst = vt + (size_t)bh * HD * L_DIM + kt * 64;
    #pragma unroll
    for (int p = 0; p < 16; ++p) {
        const int idx = tid + 256 * p;
        const int d = idx >> 6, k = idx & 63;
        dst[(size_t)d * L_DIM + k] = t[k][d];
    }
}

// ---------------------------------------------------------------------------
// MFMA flash attention. Block = (qt, bh): 128 q-rows, 4 waves x 32 rows.
// Swapped QK^T (S^T = mfma(K,Q)), online softmax, P packed-b64 to LDS, PV.
// All LDS tiles XOR-swizzled (16B chunk ^= row&7); global src pre-swizzled.
// ---------------------------------------------------------------------------
__global__ __launch_bounds__(256) void attn_mfma_kernel(
    const ushort_t* __restrict__ qn, const ushort_t* __restrict__ kn,
    const ushort_t* __restrict__ vt, float* __restrict__ ctx)
{
    __shared__ __align__(16) ushort_t Qs[128 * 64];
    __shared__ __align__(16) ushort_t Ks[64 * 64];
    __shared__ __align__(16) ushort_t Vs[64 * 64];
    __shared__ __align__(16) ushort_t Ps[4][32 * 64];

    const int qt = blockIdx.x, bh = blockIdx.y;
    const int q0 = qt * 128;
    const int tid = threadIdx.x, w = tid >> 6, lane = tid & 63;
    const int g = lane >> 4, l15 = lane & 15;
    ushort_t* Pw = &Ps[w][0];

    const ushort_t* Qg = qn + ((size_t)bh * L_DIM + q0) * HD;
    const ushort_t* Kg = kn + (size_t)bh * L_DIM * HD;
    const ushort_t* Vg = vt + (size_t)bh * HD * L_DIM;

    // stage Q (1024 x 16B chunks), source pre-swizzled
    #pragma unroll
    for (int p = 0; p < 4; ++p) {
        const int c = tid + 256 * p;
        const int row = c >> 3, ch = c & 7;
        gload16(Qg + row * 64 + ((ch ^ (row & 7)) << 3), Qs + row * 64 + (ch << 3));
    }
    __syncthreads();

    // Q fragments (constant over key loop)
    bf16x8 qf[2][2];
    #pragma unroll
    for (int mtq = 0; mtq < 2; ++mtq)
        #pragma unroll
        for (int kc = 0; kc < 2; ++kc) {
            const int row = 32 * w + 16 * mtq + l15;
            qf[mtq][kc] = *(const bf16x8*)&Qs[row * 64 + (((4 * kc + g) ^ (row & 7)) << 3)];
        }

    f32x4 o[2][4];
    float m_i[2] = {0.f, 0.f}, l_i[2] = {0.f, 0.f};
    #pragma unroll
    for (int i = 0; i < 2; ++i)
        #pragma unroll
        for (int j = 0; j < 4; ++j) o[i][j] = f32x4{0.f, 0.f, 0.f, 0.f};

    const int nkt = 2 * qt + 2;
    for (int kt = 0; kt < nkt; ++kt) {
        const int j0 = kt * 64;
        __syncthreads();   // all waves done reading Ks/Vs of prior tile
        #pragma unroll
        for (int p = 0; p < 2; ++p) {
            const int c = tid + 256 * p;
            const int row = c >> 3, ch = c & 7;
            gload16(Kg + (size_t)(j0 + row) * 64 + ((ch ^ (row & 7)) << 3),
                    Ks + row * 64 + (ch << 3));
            gload16(Vg + (size_t)row * L_DIM + j0 + ((ch ^ (row & 7)) << 3),
                    Vs + row * 64 + (ch << 3));
        }
        __syncthreads();   // staged tiles visible

        const bool active = (j0 <= q0 + 32 * w + 31);
        if (active) {
            // ---- S^T = K . Q^T ----
            bf16x8 ak[4][2];
            #pragma unroll
            for (int kt4 = 0; kt4 < 4; ++kt4)
                #pragma unroll
                for (int kc = 0; kc < 2; ++kc) {
                    const int row = 16 * kt4 + l15;
                    ak[kt4][kc] = *(const bf16x8*)&Ks[row * 64 + (((4 * kc + g) ^ (row & 7)) << 3)];
                }
            f32x4 st[4][2];
            #pragma unroll
            for (int kt4 = 0; kt4 < 4; ++kt4)
                #pragma unroll
                for (int mtq = 0; mtq < 2; ++mtq) st[kt4][mtq] = f32x4{0.f, 0.f, 0.f, 0.f};
            #pragma unroll
            for (int kc = 0; kc < 2; ++kc)
                #pragma unroll
                for (int kt4 = 0; kt4 < 4; ++kt4)
                    #pragma unroll
                    for (int mtq = 0; mtq < 2; ++mtq)
                        st[kt4][mtq] = __builtin_amdgcn_mfma_f32_16x16x32_bf16(
                            ak[kt4][kc], qf[mtq][kc], st[kt4][mtq], 0, 0, 0);

            // ---- score transform + mask + online softmax (rows lane-local) ----
            float scl[2];
            #pragma unroll
            for (int mtq = 0; mtq < 2; ++mtq) {
                const int qrow = q0 + 32 * w + 16 * mtq + l15;
                float mx = 0.0f;    // scores are >= 0
                #pragma unroll
                for (int kt4 = 0; kt4 < 4; ++kt4)
                    #pragma unroll
                    for (int r = 0; r < 4; ++r) {
                        const int key = j0 + 16 * kt4 + 4 * g + r;
                        const float x = st[kt4][mtq][r];
                        float sc = __fdividef(x * x, C_CONST - 2.f * x);
                        sc = (key > qrow) ? -1e30f : sc;
                        st[kt4][mtq][r] = sc;
                        mx = fmaxf(mx, sc);
                    }
                mx = fmaxf(mx, __shfl_xor(mx, 16));
                mx = fmaxf(mx, __shfl_xor(mx, 32));
                const float newm = fmaxf(m_i[mtq], mx);
                scl[mtq] = __expf(m_i[mtq] - newm);
                m_i[mtq] = newm;
                float ts = 0.f;
                #pragma unroll
                for (int kt4 = 0; kt4 < 4; ++kt4)
                    #pragma unroll
                    for (int r = 0; r < 4; ++r) {
                        const float pv = __expf(st[kt4][mtq][r] - newm);
                        st[kt4][mtq][r] = pv;
                        ts += pv;
                    }
                ts += __shfl_xor(ts, 16);
                ts += __shfl_xor(ts, 32);
                l_i[mtq] = l_i[mtq] * scl[mtq] + ts;
            }

            // ---- pack P -> LDS (b64, 4 consecutive keys per lane) ----
            #pragma unroll
            for (int mtq = 0; mtq < 2; ++mtq) {
                const int qr = 16 * mtq + l15;
                #pragma unroll
                for (int kt4 = 0; kt4 < 4; ++kt4) {
                    const int ch = 2 * kt4 + (g >> 1);
                    uint2 pk;
                    pk.x = f2bf(st[kt4][mtq][0]) | (f2bf(st[kt4][mtq][1]) << 16);
                    pk.y = f2bf(st[kt4][mtq][2]) | (f2bf(st[kt4][mtq][3]) << 16);
                    *(uint2*)&Pw[qr * 64 + ((ch ^ (qr & 7)) << 3) + 4 * (g & 1)] = pk;
                }
            }

            // ---- rescale O ----
            #pragma unroll
            for (int mtq = 0; mtq < 2; ++mtq)
                #pragma unroll
                for (int r = 0; r < 4; ++r) {
                    const float s = __shfl(scl[mtq], 4 * (lane >> 4) + r);
                    #pragma unroll
                    for (int dt = 0; dt < 4; ++dt) o[mtq][dt][r] *= s;
                }

            // ---- O += P . V ----
            bf16x8 ap[2][2], av[4][2];
            #pragma unroll
            for (int mtq = 0; mtq < 2; ++mtq)
                #pragma unroll
                for (int kc = 0; kc < 2; ++kc) {
                    const int row = 16 * mtq + l15;
                    ap[mtq][kc] = *(const bf16x8*)&Pw[row * 64 + (((4 * kc + g) ^ (row & 7)) << 3)];
                }
            #pragma unroll
            for (int dt = 0; dt < 4; ++dt)
                #pragma unroll
                for (int kc = 0; kc < 2; ++kc) {
                    const int row = 16 * dt + l15;
                    av[dt][kc] = *(const bf16x8*)&Vs[row * 64 + (((4 * kc + g) ^ (row & 7)) << 3)];
                }
            #pragma unroll
            for (int kc = 0; kc < 2; ++kc)
                #pragma unroll
                for (int mtq = 0; mtq < 2; ++mtq)
                    #pragma unroll
                    for (int dt = 0; dt < 4; ++dt)
                        o[mtq][dt] = __builtin_amdgcn_mfma_f32_16x16x32_bf16(
                            ap[mtq][kc], av[dt][kc], o[mtq][dt], 0, 0, 0);
        }
    }

    // ---- epilogue: divide by l, store fp32 ctx ----
    float* Og = ctx + ((size_t)bh * L_DIM + q0 + 32 * w) * HD;
    #pragma unroll
    for (int mtq = 0; mtq < 2; ++mtq)
        #pragma unroll
        for (int r = 0; r < 4; ++r) {
            const float lv = __shfl(l_i[mtq], 4 * (lane >> 4) + r);
            const float inv = 1.0f / lv;
            #pragma unroll
            for (int dt = 0; dt < 4; ++dt)
                Og[(size_t)(16 * mtq + 4 * g + r) * HD + 16 * dt + l15] = o[mtq][dt][r] * inv;
        }
}

// ---------------------------------------------------------------------------
extern "C" void kernel_launch(void* const* d_in, const int* in_sizes, int n_in,
                              void* d_out, int out_size, void* d_ws, size_t ws_size,
                              hipStream_t stream)
{
    const float* x    = (const float*)d_in[0];
    const float* Wqkv = (const float*)d_in[1];
    const float* bqkv = (const float*)d_in[2];
    const float* Wout = (const float*)d_in[3];
    const float* bout = (const float*)d_in[4];
    float* out = (float*)d_out;

    char* ws = (char*)d_ws;
    const size_t MB = 1u << 20;
    float*    qb    = (float*)   (ws + 0 * MB);    // [0,16) fp32 q
    float*    kb    = (float*)   (ws + 16 * MB);   // [16,32) fp32 k
    ushort_t* vb16  = (ushort_t*)(ws + 32 * MB);   // [32,40) bf16 v
    ushort_t* xb    = (ushort_t*)(ws + 40 * MB);   // [40,48) bf16 x     (dead after qkv gemm)
    ushort_t* WqkvT = (ushort_t*)(ws + 48 * MB);   // [48,54)            (dead after qkv gemm)
    ushort_t* kn16  = (ushort_t*)(ws + 40 * MB);   // reuse xb slot
    ushort_t* qn16  = (ushort_t*)(ws + 48 * MB);   // reuse WqkvT slot
    ushort_t* vt16  = (ushort_t*)(ws + 56 * MB);   // [56,64)
    float*    ctx   = (float*)   (ws + 0 * MB);    // reuse qb slot (qb dead after normalize)
    ushort_t* cb    = (ushort_t*)(ws + 16 * MB);   // reuse kb slot
    ushort_t* WoutT = (ushort_t*)(ws + 24 * MB);   // [24,26)

    // 1) bf16 copies for the qkv GEMM
    cast_bf16_kernel<<<4096, 256, 0, stream>>>(x, xb, (M_ROWS * E_DIM) / 4);
    transpose_bf16_kernel<<<dim3(QKV_N / 64, E_DIM / 64), 256, 0, stream>>>(Wqkv, WqkvT, E_DIM, QKV_N);

    // 2) qkv GEMM: q,k fp32; v bf16
    gemm_bt_kernel<QKV_N, 0><<<dim3(M_ROWS / 128, QKV_N / 128), 256, 0, stream>>>(
        xb, WqkvT, bqkv, qb, kb, vb16);

    // 3) normalize q,k -> bf16
    const int nrows = B_DIM * H_DIM * L_DIM;  // 65536
    normalize_bf16_kernel<<<nrows / 4, 256, 0, stream>>>(qb, qn16);
    normalize_bf16_kernel<<<nrows / 4, 256, 0, stream>>>(kb, kn16);

    // 4) transpose v -> vt16 [bh][d][key]
    vt_transpose_kernel<<<dim3(L_DIM / 64, B_DIM * H_DIM), 256, 0, stream>>>(vb16, vt16);

    // 5) MFMA flash attention
    attn_mfma_kernel<<<dim3(L_DIM / 128, B_DIM * H_DIM), 256, 0, stream>>>(qn16, kn16, vt16, ctx);

    // 6) gather ctx -> bf16 [M][E]; transpose W_out
    gather_ctx_kernel<<<4096, 256, 0, stream>>>(ctx, cb);
    transpose_bf16_kernel<<<dim3(E_DIM / 64, E_DIM / 64), 256, 0, stream>>>(Wout, WoutT, E_DIM, E_DIM);

    // 7) out = ctx @ W_out + b (MFMA)
    gemm_bt_kernel<E_DIM, 1><<<dim3(M_ROWS / 128, E_DIM / 128), 256, 0, stream>>>(
        cb, WoutT, bout, out, nullptr, nullptr);
}